// Round 1
// baseline (36.758 us; speedup 1.0000x reference)
//
#include <hip/hip_runtime.h>
#include <math.h>

#define NANCH 8400
#define ROWL  37
#define H0    2160
#define W0    3840
#define HW    (H0 * W0)
#define NPART 33

// ws layout (floats)
#define COEF_OFF  0            // 32 floats: final coef
#define FB_OFF    32           // 4 floats: scaled final box (x1,y1,x2,y2) in full-res coords
#define PART_OFF  40           // NPART*6 floats of per-block partials
#define LOGIT_OFF 256          // 160*160 mask logits
#define SIG_OFF   (256 + 25600) // 640*640 sigmoid map
// total = 435456 floats = ~1.74 MB

// ---------------------------------------------------------------------------
// K1: per-block partials: max over boxes region, argmax of score under both
// is_norm hypotheses. One anchor per thread (33*256 = 8448 >= 8400).
// ---------------------------------------------------------------------------
__global__ void k_score(const float* __restrict__ pred, float* __restrict__ wsf) {
    int tid = threadIdx.x;
    int t = blockIdx.x * blockDim.x + tid;

    float bmax = -1e30f;
    float vT = -1e30f, vF = -1e30f;
    int   iT = 0, iF = 0;

    if (t < NANCH) {
        const float* row = pred + t * ROWL;
        float cx = row[0], cy = row[1], w = row[2], h = row[3];
        bmax = fmaxf(fmaxf(cx, cy), fmaxf(w, h));

        float l  = row[4];
        float sc = 1.0f / (1.0f + expf(-l));
        float base = fmaxf(sc - 0.5f, 0.0f) + 0.001f;

        float sum = 0.0f;
#pragma unroll
        for (int j = 0; j < 32; ++j) sum += fabsf(row[5 + j]);
        float sb = base * (sum * 0.03125f);   // * maskness (global norm is argmax-invariant)

        // center weight, is_norm = true (cx,cy scaled by 640)
        float cx6 = cx * 640.0f, cy6 = cy * 640.0f;
        float dxT = fabsf(cx6 - 320.0f) / 320.0f;
        float dyT = fabsf(cy6 - 320.0f) / 320.0f;
        float cwT = fminf(fmaxf(1.0f - 0.5f * (dxT + dyT), 0.0f), 1.0f);
        // is_norm = false (raw cx,cy)
        float dxF = fabsf(cx - 320.0f) / 320.0f;
        float dyF = fabsf(cy - 320.0f) / 320.0f;
        float cwF = fminf(fmaxf(1.0f - 0.5f * (dxF + dyF), 0.0f), 1.0f);

        vT = sb * (0.5f + 0.5f * cwT); iT = t;
        vF = sb * (0.5f + 0.5f * cwF); iF = t;
    }

    __shared__ float sb_[256];
    __shared__ float svT[256]; __shared__ int siT[256];
    __shared__ float svF[256]; __shared__ int siF[256];
    sb_[tid] = bmax;
    svT[tid] = vT; siT[tid] = iT;
    svF[tid] = vF; siF[tid] = iF;
    __syncthreads();

    for (int off = 128; off > 0; off >>= 1) {
        if (tid < off) {
            sb_[tid] = fmaxf(sb_[tid], sb_[tid + off]);
            float ov = svT[tid + off]; int oi = siT[tid + off];
            if (ov > svT[tid] || (ov == svT[tid] && oi < siT[tid])) { svT[tid] = ov; siT[tid] = oi; }
            ov = svF[tid + off]; oi = siF[tid + off];
            if (ov > svF[tid] || (ov == svF[tid] && oi < siF[tid])) { svF[tid] = ov; siF[tid] = oi; }
        }
        __syncthreads();
    }

    if (tid == 0) {
        float* p = wsf + PART_OFF + blockIdx.x * 6;
        int*   q = (int*)p;
        p[0] = sb_[0];
        p[1] = svT[0]; q[2] = siT[0];
        p[3] = svF[0]; q[4] = siF[0];
    }
}

// ---------------------------------------------------------------------------
// K2: merge partials, decide is_norm, pick winner; write coef[32] + scaled box
// ---------------------------------------------------------------------------
__global__ void k_finalize(const float* __restrict__ pred, float* __restrict__ wsf) {
    __shared__ int s_bi;
    if (threadIdx.x == 0) {
        float bmax = -1e30f;
        float vT = -1e30f, vF = -1e30f;
        int   iT = 0, iF = 0;
        for (int b = 0; b < NPART; ++b) {
            const float* p = wsf + PART_OFF + b * 6;
            const int*   q = (const int*)p;
            bmax = fmaxf(bmax, p[0]);
            if (p[1] > vT || (p[1] == vT && q[2] < iT)) { vT = p[1]; iT = q[2]; }
            if (p[3] > vF || (p[3] == vF && q[4] < iF)) { vF = p[3]; iF = q[4]; }
        }
        bool is_norm = (bmax <= 1.2f);
        s_bi = is_norm ? iT : iF;
    }
    __syncthreads();
    int bi = s_bi;
    if (threadIdx.x < 32) {
        wsf[COEF_OFF + threadIdx.x] = pred[bi * ROWL + 5 + threadIdx.x];
    }
    if (threadIdx.x == 32) {
        const float* row = pred + bi * ROWL;
        float cx = row[0], cy = row[1], w = row[2], h = row[3];
        float x1 = fminf(fmaxf(cx - w * 0.5f, 0.0f), 639.0f);
        float y1 = fminf(fmaxf(cy - h * 0.5f, 0.0f), 639.0f);
        float x2 = fminf(fmaxf(cx + w * 0.5f, 0.0f), 639.0f);
        float y2 = fminf(fmaxf(cy + h * 0.5f, 0.0f), 639.0f);
        wsf[FB_OFF + 0] = x1 * 6.0f;     // sx = 3840/640
        wsf[FB_OFF + 1] = y1 * 3.375f;   // sy = 2160/640
        wsf[FB_OFF + 2] = x2 * 6.0f;
        wsf[FB_OFF + 3] = y2 * 3.375f;
    }
}

// ---------------------------------------------------------------------------
// K3: mask logits 160x160 = coef[32] . proto[32][25600]
// ---------------------------------------------------------------------------
__global__ void k_logits(const float* __restrict__ proto, const float* __restrict__ wsf,
                         float* __restrict__ logits) {
    __shared__ float c[32];
    if (threadIdx.x < 32) c[threadIdx.x] = wsf[COEF_OFF + threadIdx.x];
    __syncthreads();
    int p = blockIdx.x * blockDim.x + threadIdx.x;
    if (p < 25600) {
        float s = 0.0f;
#pragma unroll
        for (int j = 0; j < 32; ++j) s += c[j] * proto[j * 25600 + p];
        logits[p] = s;
    }
}

// ---------------------------------------------------------------------------
// K4: sigmoid(bilinear upsample 160->640). half-pixel centers, clamp edges.
// ---------------------------------------------------------------------------
__global__ void k_sig640(const float* __restrict__ logits, float* __restrict__ sig) {
    int t = blockIdx.x * blockDim.x + threadIdx.x;
    if (t >= 640 * 640) return;
    int y = t / 640, x = t - y * 640;

    float yf = y * 0.25f - 0.375f;   // (y+0.5)/4 - 0.5, exact in f32
    float xf = x * 0.25f - 0.375f;
    int y0 = (int)floorf(yf); float wy = yf - (float)y0;
    int x0 = (int)floorf(xf); float wx = xf - (float)x0;
    int y0c = max(y0, 0), y1c = min(y0 + 1, 159);
    int x0c = max(x0, 0), x1c = min(x0 + 1, 159);

    float a = logits[y0c * 160 + x0c], b = logits[y0c * 160 + x1c];
    float c = logits[y1c * 160 + x0c], d = logits[y1c * 160 + x1c];
    float v = (1.0f - wy) * ((1.0f - wx) * a + wx * b)
            +         wy  * ((1.0f - wx) * c + wx * d);
    sig[t] = 1.0f / (1.0f + expf(-v));
}

// ---------------------------------------------------------------------------
// K5: paint output. One thread = 4 consecutive x-pixels, 3 channels.
// Outside rect: write zeros, never touch x_raw (store-BW bound).
// ---------------------------------------------------------------------------
__global__ __launch_bounds__(256) void k_paint(const float* __restrict__ x_raw,
                                               const float* __restrict__ sig,
                                               const float* __restrict__ wsf,
                                               float* __restrict__ out) {
    int t = blockIdx.x * blockDim.x + threadIdx.x;  // 2160*960 quads
    int Y  = t / 960;
    int xq = t - Y * 960;
    int X0 = xq * 4;
    int pix = Y * W0 + X0;

    const float4 fb = *(const float4*)(wsf + FB_OFF);
    float ysf = (float)Y;
    bool yin = (ysf >= fb.y) && (ysf < fb.w);
    bool xin = ((float)(X0 + 3) >= fb.x) && ((float)X0 < fb.z);

    float4 o0 = make_float4(0.f, 0.f, 0.f, 0.f);
    float4 o1 = o0, o2 = o0;

    if (yin && xin) {
        float yf = (ysf + 0.5f) / 3.375f - 0.5f;   // 640/2160 scale
        int   y0 = (int)floorf(yf);
        float wy = yf - (float)y0;
        int y0c = max(y0, 0), y1c = min(y0 + 1, 639);
        const float* S0 = sig + y0c * 640;
        const float* S1 = sig + y1c * 640;

        float m[4];
#pragma unroll
        for (int k = 0; k < 4; ++k) {
            float xs = (float)(X0 + k);
            bool rect = (xs >= fb.x) && (xs < fb.z);
            float xf = (xs + 0.5f) / 6.0f - 0.5f;  // 640/3840 scale
            int   x0 = (int)floorf(xf);
            float wx = xf - (float)x0;
            int x0c = max(x0, 0), x1c = min(x0 + 1, 639);
            float v = (1.0f - wy) * ((1.0f - wx) * S0[x0c] + wx * S0[x1c])
                    +         wy  * ((1.0f - wx) * S1[x0c] + wx * S1[x1c]);
            m[k] = (rect && (v > 0.72f)) ? 1.0f : 0.0f;
        }

        float4 xa = *(const float4*)(x_raw + pix);
        float4 xb = *(const float4*)(x_raw + HW + pix);
        float4 xc = *(const float4*)(x_raw + 2 * HW + pix);
#define CLIP255(v) fminf(fmaxf((v) * 255.0f, 0.0f), 255.0f)
        o0 = make_float4(m[0] * CLIP255(xa.x), m[1] * CLIP255(xa.y),
                         m[2] * CLIP255(xa.z), m[3] * CLIP255(xa.w));
        o1 = make_float4(m[0] * CLIP255(xb.x), m[1] * CLIP255(xb.y),
                         m[2] * CLIP255(xb.z), m[3] * CLIP255(xb.w));
        o2 = make_float4(m[0] * CLIP255(xc.x), m[1] * CLIP255(xc.y),
                         m[2] * CLIP255(xc.z), m[3] * CLIP255(xc.w));
#undef CLIP255
    }

    *(float4*)(out + pix)          = o0;
    *(float4*)(out + HW + pix)     = o1;
    *(float4*)(out + 2 * HW + pix) = o2;
}

// ---------------------------------------------------------------------------
extern "C" void kernel_launch(void* const* d_in, const int* in_sizes, int n_in,
                              void* d_out, int out_size, void* d_ws, size_t ws_size,
                              hipStream_t stream) {
    const float* x_raw = (const float*)d_in[0];
    const float* pred  = (const float*)d_in[1];
    const float* proto = (const float*)d_in[2];
    float* out = (float*)d_out;
    float* wsf = (float*)d_ws;

    k_score   <<<dim3(NPART), dim3(256), 0, stream>>>(pred, wsf);
    k_finalize<<<dim3(1),     dim3(64),  0, stream>>>(pred, wsf);
    k_logits  <<<dim3(100),   dim3(256), 0, stream>>>(proto, wsf, wsf + LOGIT_OFF);
    k_sig640  <<<dim3(1600),  dim3(256), 0, stream>>>(wsf + LOGIT_OFF, wsf + SIG_OFF);
    k_paint   <<<dim3(8100),  dim3(256), 0, stream>>>(x_raw, wsf + SIG_OFF, wsf, out);
}